// Round 1
// baseline (4575.809 us; speedup 1.0000x reference)
//
#include <hip/hip_runtime.h>
#include <cmath>

#define BS   2
#define SEQ  2048
#define DM   1024
#define NH   16
#define HD   64
#define D3   3072
#define MROWS (BS * SEQ)   // 4096

// ---------------------------------------------------------------------------
// Generic fp32 GEMM:  C[M][NDIM] = A[M][KDIM] @ W[NDIM][KDIM]^T + bias
// tile 128x128, K-tile 16, 256 threads, 8x8 per-thread micro-tile.
// LDS tiles stored transposed: As[k][row] so fragment reads are float4.
// ---------------------------------------------------------------------------
template<int KDIM, int NDIM>
__global__ __launch_bounds__(256) void gemm_bias_kernel(
    const float* __restrict__ A, const float* __restrict__ W,
    const float* __restrict__ bias, float* __restrict__ C)
{
    __shared__ float As[16][128];
    __shared__ float Bs[16][128];

    const int tid = threadIdx.x;
    const int tx = tid & 15;        // micro-tile col group
    const int ty = tid >> 4;        // micro-tile row group
    const int lr = tid >> 1;        // loader: row within tile (0..127)
    const int lc = (tid & 1) * 8;   // loader: col chunk (0 or 8)

    const int bx = blockIdx.x;      // N tile
    const int by = blockIdx.y;      // M tile

    float acc[8][8];
#pragma unroll
    for (int i = 0; i < 8; ++i)
#pragma unroll
        for (int j = 0; j < 8; ++j) acc[i][j] = 0.f;

    const size_t arow = (size_t)(by * 128 + lr) * KDIM;
    const size_t wrow = (size_t)(bx * 128 + lr) * KDIM;

    for (int c0 = 0; c0 < KDIM; c0 += 16) {
        float4 a0 = *(const float4*)(A + arow + c0 + lc);
        float4 a1 = *(const float4*)(A + arow + c0 + lc + 4);
        float4 b0 = *(const float4*)(W + wrow + c0 + lc);
        float4 b1 = *(const float4*)(W + wrow + c0 + lc + 4);

        __syncthreads();   // previous iteration finished reading LDS
        As[lc + 0][lr] = a0.x; As[lc + 1][lr] = a0.y;
        As[lc + 2][lr] = a0.z; As[lc + 3][lr] = a0.w;
        As[lc + 4][lr] = a1.x; As[lc + 5][lr] = a1.y;
        As[lc + 6][lr] = a1.z; As[lc + 7][lr] = a1.w;
        Bs[lc + 0][lr] = b0.x; Bs[lc + 1][lr] = b0.y;
        Bs[lc + 2][lr] = b0.z; Bs[lc + 3][lr] = b0.w;
        Bs[lc + 4][lr] = b1.x; Bs[lc + 5][lr] = b1.y;
        Bs[lc + 6][lr] = b1.z; Bs[lc + 7][lr] = b1.w;
        __syncthreads();

#pragma unroll
        for (int kk = 0; kk < 16; ++kk) {
            float4 aL = *(const float4*)&As[kk][ty * 8];
            float4 aH = *(const float4*)&As[kk][ty * 8 + 4];
            float4 bL = *(const float4*)&Bs[kk][tx * 8];
            float4 bH = *(const float4*)&Bs[kk][tx * 8 + 4];
            float av[8] = {aL.x, aL.y, aL.z, aL.w, aH.x, aH.y, aH.z, aH.w};
            float bv[8] = {bL.x, bL.y, bL.z, bL.w, bH.x, bH.y, bH.z, bH.w};
#pragma unroll
            for (int i = 0; i < 8; ++i)
#pragma unroll
                for (int j = 0; j < 8; ++j)
                    acc[i][j] += av[i] * bv[j];
        }
    }

    const int ncol = bx * 128 + tx * 8;
    float4 bias0 = *(const float4*)(bias + ncol);
    float4 bias1 = *(const float4*)(bias + ncol + 4);
#pragma unroll
    for (int i = 0; i < 8; ++i) {
        const int m = by * 128 + ty * 8 + i;
        float4 o0, o1;
        o0.x = acc[i][0] + bias0.x; o0.y = acc[i][1] + bias0.y;
        o0.z = acc[i][2] + bias0.z; o0.w = acc[i][3] + bias0.w;
        o1.x = acc[i][4] + bias1.x; o1.y = acc[i][5] + bias1.y;
        o1.z = acc[i][6] + bias1.z; o1.w = acc[i][7] + bias1.w;
        *(float4*)(C + (size_t)m * NDIM + ncol)     = o0;
        *(float4*)(C + (size_t)m * NDIM + ncol + 4) = o1;
    }
}

// ---------------------------------------------------------------------------
// QKV projection GEMM: A-row is concat(q_row, k_row, v_row); same structure.
// K-tile (16) never straddles a 1024-boundary, so segment chosen per tile.
// ---------------------------------------------------------------------------
__global__ __launch_bounds__(256) void qkv_gemm_kernel(
    const float* __restrict__ Aq, const float* __restrict__ Ak,
    const float* __restrict__ Av, const float* __restrict__ W,
    const float* __restrict__ bias, float* __restrict__ C)
{
    __shared__ float As[16][128];
    __shared__ float Bs[16][128];

    const int tid = threadIdx.x;
    const int tx = tid & 15;
    const int ty = tid >> 4;
    const int lr = tid >> 1;
    const int lc = (tid & 1) * 8;

    const int bx = blockIdx.x;      // N tile (24)
    const int by = blockIdx.y;      // M tile (32)

    float acc[8][8];
#pragma unroll
    for (int i = 0; i < 8; ++i)
#pragma unroll
        for (int j = 0; j < 8; ++j) acc[i][j] = 0.f;

    const size_t arow_base = (size_t)(by * 128 + lr) * DM;   // per-segment row
    const size_t wrow = (size_t)(bx * 128 + lr) * D3;

    for (int c0 = 0; c0 < D3; c0 += 16) {
        const int seg = c0 >> 10;
        const float* Asrc = (seg == 0) ? Aq : ((seg == 1) ? Ak : Av);
        const int cl = (c0 & 1023) + lc;

        float4 a0 = *(const float4*)(Asrc + arow_base + cl);
        float4 a1 = *(const float4*)(Asrc + arow_base + cl + 4);
        float4 b0 = *(const float4*)(W + wrow + c0 + lc);
        float4 b1 = *(const float4*)(W + wrow + c0 + lc + 4);

        __syncthreads();
        As[lc + 0][lr] = a0.x; As[lc + 1][lr] = a0.y;
        As[lc + 2][lr] = a0.z; As[lc + 3][lr] = a0.w;
        As[lc + 4][lr] = a1.x; As[lc + 5][lr] = a1.y;
        As[lc + 6][lr] = a1.z; As[lc + 7][lr] = a1.w;
        Bs[lc + 0][lr] = b0.x; Bs[lc + 1][lr] = b0.y;
        Bs[lc + 2][lr] = b0.z; Bs[lc + 3][lr] = b0.w;
        Bs[lc + 4][lr] = b1.x; Bs[lc + 5][lr] = b1.y;
        Bs[lc + 6][lr] = b1.z; Bs[lc + 7][lr] = b1.w;
        __syncthreads();

#pragma unroll
        for (int kk = 0; kk < 16; ++kk) {
            float4 aL = *(const float4*)&As[kk][ty * 8];
            float4 aH = *(const float4*)&As[kk][ty * 8 + 4];
            float4 bL = *(const float4*)&Bs[kk][tx * 8];
            float4 bH = *(const float4*)&Bs[kk][tx * 8 + 4];
            float av[8] = {aL.x, aL.y, aL.z, aL.w, aH.x, aH.y, aH.z, aH.w};
            float bv[8] = {bL.x, bL.y, bL.z, bL.w, bH.x, bH.y, bH.z, bH.w};
#pragma unroll
            for (int i = 0; i < 8; ++i)
#pragma unroll
                for (int j = 0; j < 8; ++j)
                    acc[i][j] += av[i] * bv[j];
        }
    }

    const int ncol = bx * 128 + tx * 8;
    float4 bias0 = *(const float4*)(bias + ncol);
    float4 bias1 = *(const float4*)(bias + ncol + 4);
#pragma unroll
    for (int i = 0; i < 8; ++i) {
        const int m = by * 128 + ty * 8 + i;
        float4 o0, o1;
        o0.x = acc[i][0] + bias0.x; o0.y = acc[i][1] + bias0.y;
        o0.z = acc[i][2] + bias0.z; o0.w = acc[i][3] + bias0.w;
        o1.x = acc[i][4] + bias1.x; o1.y = acc[i][5] + bias1.y;
        o1.z = acc[i][6] + bias1.z; o1.w = acc[i][7] + bias1.w;
        *(float4*)(C + (size_t)m * D3 + ncol)     = o0;
        *(float4*)(C + (size_t)m * D3 + ncol + 4) = o1;
    }
}

// ---------------------------------------------------------------------------
// Flash-style attention, fp32. One q-row per thread (q,o in regs).
// K/V rows are wave-uniform global reads (expect s_load scalarization).
// grid = B*H*(S/256) = 256 blocks of 256 threads.
// qkv layout: [4096][3072] rows = (b*S+s), cols: [0,1024)=q, [1024,2048)=k,
// [2048,3072)=v; head h occupies 64 cols at h*64 within each segment.
// Output: attn[(b*S+s)*1024 + h*64 + d]  (combine-heads layout).
// ---------------------------------------------------------------------------
#define KC 16

__global__ __launch_bounds__(256) void attn_kernel(
    const float* __restrict__ qkv, float* __restrict__ attn)
{
    const int bid = blockIdx.x;
    const int b  = bid / (NH * (SEQ / 256));
    const int rem = bid % (NH * (SEQ / 256));
    const int h  = rem / (SEQ / 256);
    const int qt = rem % (SEQ / 256);
    const int srow = qt * 256 + threadIdx.x;

    const float* qptr  = qkv + ((size_t)(b * SEQ + srow)) * D3 + h * HD;
    const float* kbase = qkv + (size_t)b * SEQ * D3 + DM     + h * HD;
    const float* vbase = qkv + (size_t)b * SEQ * D3 + 2 * DM + h * HD;

    float qv[HD];
#pragma unroll
    for (int d = 0; d < HD; d += 4) {
        float4 t = *(const float4*)(qptr + d);
        qv[d] = t.x; qv[d+1] = t.y; qv[d+2] = t.z; qv[d+3] = t.w;
    }

    float o[HD];
#pragma unroll
    for (int d = 0; d < HD; ++d) o[d] = 0.f;
    float mrun = -INFINITY;
    float lrun = 0.f;

    for (int kk0 = 0; kk0 < SEQ; kk0 += KC) {
        float sc[KC];
#pragma unroll
        for (int j = 0; j < KC; ++j) {
            const float* kr = kbase + (size_t)(kk0 + j) * D3;
            float acc = 0.f;
#pragma unroll
            for (int d = 0; d < HD; d += 4) {
                float4 t = *(const float4*)(kr + d);   // wave-uniform address
                acc += qv[d] * t.x + qv[d+1] * t.y + qv[d+2] * t.z + qv[d+3] * t.w;
            }
            sc[j] = acc * 0.125f;   // 1/sqrt(64)
        }

        float mt = sc[0];
#pragma unroll
        for (int j = 1; j < KC; ++j) mt = fmaxf(mt, sc[j]);
        const float mnew = fmaxf(mrun, mt);
        const float scale = __expf(mrun - mnew);   // exp(-inf)=0 on first tile

        float lsum = 0.f;
#pragma unroll
        for (int j = 0; j < KC; ++j) {
            sc[j] = __expf(sc[j] - mnew);
            lsum += sc[j];
        }
        lrun = lrun * scale + lsum;
#pragma unroll
        for (int d = 0; d < HD; ++d) o[d] *= scale;

#pragma unroll
        for (int j = 0; j < KC; ++j) {
            const float* vr = vbase + (size_t)(kk0 + j) * D3;
            const float pj = sc[j];
#pragma unroll
            for (int d = 0; d < HD; d += 4) {
                float4 t = *(const float4*)(vr + d);   // wave-uniform address
                o[d]   += pj * t.x; o[d+1] += pj * t.y;
                o[d+2] += pj * t.z; o[d+3] += pj * t.w;
            }
        }
        mrun = mnew;
    }

    const float inv = 1.f / lrun;
    float* op = attn + ((size_t)(b * SEQ + srow)) * DM + h * HD;
#pragma unroll
    for (int d = 0; d < HD; d += 4) {
        float4 t;
        t.x = o[d] * inv; t.y = o[d+1] * inv;
        t.z = o[d+2] * inv; t.w = o[d+3] * inv;
        *(float4*)(op + d) = t;
    }
}

// ---------------------------------------------------------------------------
extern "C" void kernel_launch(void* const* d_in, const int* in_sizes, int n_in,
                              void* d_out, int out_size, void* d_ws, size_t ws_size,
                              hipStream_t stream) {
    const float* q    = (const float*)d_in[0];
    const float* k    = (const float*)d_in[1];
    const float* v    = (const float*)d_in[2];
    const float* Wqkv = (const float*)d_in[3];
    const float* bqkv = (const float*)d_in[4];
    const float* Wo   = (const float*)d_in[5];
    const float* bo   = (const float*)d_in[6];
    float* out = (float*)d_out;

    float* qkv  = (float*)d_ws;                       // [4096][3072] fp32
    float* attn = qkv + (size_t)MROWS * D3;           // [4096][1024] fp32

    // 1) QKV projection
    {
        dim3 grid(D3 / 128, MROWS / 128);             // 24 x 32
        qkv_gemm_kernel<<<grid, 256, 0, stream>>>(q, k, v, Wqkv, bqkv, qkv);
    }
    // 2) attention
    {
        dim3 grid(BS * NH * (SEQ / 256));             // 256
        attn_kernel<<<grid, 256, 0, stream>>>(qkv, attn);
    }
    // 3) output projection
    {
        dim3 grid(DM / 128, MROWS / 128);             // 8 x 32
        gemm_bias_kernel<DM, DM><<<grid, 256, 0, stream>>>(attn, Wo, bo, out);
    }
}

// Round 2
// 1234.003 us; speedup vs baseline: 3.7081x; 3.7081x over previous
//
#include <hip/hip_runtime.h>
#include <cmath>

#define BS   2
#define SEQ  2048
#define DM   1024
#define NH   16
#define HD   64
#define D3   3072
#define MROWS (BS * SEQ)   // 4096
#define KVBLK 64
#define QBLK  128

typedef __attribute__((ext_vector_type(8))) short short8;
typedef __attribute__((ext_vector_type(4))) float f32x4;

__device__ __forceinline__ unsigned short f2bf(float f) {
    unsigned u = __builtin_bit_cast(unsigned, f);
    u += 0x7fff + ((u >> 16) & 1);          // RNE
    return (unsigned short)(u >> 16);
}
__device__ __forceinline__ float bf2f(unsigned short h) {
    unsigned u = ((unsigned)h) << 16;
    return __builtin_bit_cast(float, u);
}

// ---------------------------------------------------------------------------
// fp32 GEMM (unchanged from round 1):  C = A @ W^T + bias
// ---------------------------------------------------------------------------
template<int KDIM, int NDIM>
__global__ __launch_bounds__(256) void gemm_bias_kernel(
    const float* __restrict__ A, const float* __restrict__ W,
    const float* __restrict__ bias, float* __restrict__ C)
{
    __shared__ float As[16][128];
    __shared__ float Bs[16][128];

    const int tid = threadIdx.x;
    const int tx = tid & 15;
    const int ty = tid >> 4;
    const int lr = tid >> 1;
    const int lc = (tid & 1) * 8;
    const int bx = blockIdx.x;
    const int by = blockIdx.y;

    float acc[8][8];
#pragma unroll
    for (int i = 0; i < 8; ++i)
#pragma unroll
        for (int j = 0; j < 8; ++j) acc[i][j] = 0.f;

    const size_t arow = (size_t)(by * 128 + lr) * KDIM;
    const size_t wrow = (size_t)(bx * 128 + lr) * KDIM;

    for (int c0 = 0; c0 < KDIM; c0 += 16) {
        float4 a0 = *(const float4*)(A + arow + c0 + lc);
        float4 a1 = *(const float4*)(A + arow + c0 + lc + 4);
        float4 b0 = *(const float4*)(W + wrow + c0 + lc);
        float4 b1 = *(const float4*)(W + wrow + c0 + lc + 4);

        __syncthreads();
        As[lc + 0][lr] = a0.x; As[lc + 1][lr] = a0.y;
        As[lc + 2][lr] = a0.z; As[lc + 3][lr] = a0.w;
        As[lc + 4][lr] = a1.x; As[lc + 5][lr] = a1.y;
        As[lc + 6][lr] = a1.z; As[lc + 7][lr] = a1.w;
        Bs[lc + 0][lr] = b0.x; Bs[lc + 1][lr] = b0.y;
        Bs[lc + 2][lr] = b0.z; Bs[lc + 3][lr] = b0.w;
        Bs[lc + 4][lr] = b1.x; Bs[lc + 5][lr] = b1.y;
        Bs[lc + 6][lr] = b1.z; Bs[lc + 7][lr] = b1.w;
        __syncthreads();

#pragma unroll
        for (int kk = 0; kk < 16; ++kk) {
            float4 aL = *(const float4*)&As[kk][ty * 8];
            float4 aH = *(const float4*)&As[kk][ty * 8 + 4];
            float4 bL = *(const float4*)&Bs[kk][tx * 8];
            float4 bH = *(const float4*)&Bs[kk][tx * 8 + 4];
            float av[8] = {aL.x, aL.y, aL.z, aL.w, aH.x, aH.y, aH.z, aH.w};
            float bv[8] = {bL.x, bL.y, bL.z, bL.w, bH.x, bH.y, bH.z, bH.w};
#pragma unroll
            for (int i = 0; i < 8; ++i)
#pragma unroll
                for (int j = 0; j < 8; ++j)
                    acc[i][j] += av[i] * bv[j];
        }
    }

    const int ncol = bx * 128 + tx * 8;
    float4 bias0 = *(const float4*)(bias + ncol);
    float4 bias1 = *(const float4*)(bias + ncol + 4);
#pragma unroll
    for (int i = 0; i < 8; ++i) {
        const int m = by * 128 + ty * 8 + i;
        float4 o0, o1;
        o0.x = acc[i][0] + bias0.x; o0.y = acc[i][1] + bias0.y;
        o0.z = acc[i][2] + bias0.z; o0.w = acc[i][3] + bias0.w;
        o1.x = acc[i][4] + bias1.x; o1.y = acc[i][5] + bias1.y;
        o1.z = acc[i][6] + bias1.z; o1.w = acc[i][7] + bias1.w;
        *(float4*)(C + (size_t)m * NDIM + ncol)     = o0;
        *(float4*)(C + (size_t)m * NDIM + ncol + 4) = o1;
    }
}

// ---------------------------------------------------------------------------
// QKV projection GEMM (unchanged from round 1)
// ---------------------------------------------------------------------------
__global__ __launch_bounds__(256) void qkv_gemm_kernel(
    const float* __restrict__ Aq, const float* __restrict__ Ak,
    const float* __restrict__ Av, const float* __restrict__ W,
    const float* __restrict__ bias, float* __restrict__ C)
{
    __shared__ float As[16][128];
    __shared__ float Bs[16][128];

    const int tid = threadIdx.x;
    const int tx = tid & 15;
    const int ty = tid >> 4;
    const int lr = tid >> 1;
    const int lc = (tid & 1) * 8;
    const int bx = blockIdx.x;
    const int by = blockIdx.y;

    float acc[8][8];
#pragma unroll
    for (int i = 0; i < 8; ++i)
#pragma unroll
        for (int j = 0; j < 8; ++j) acc[i][j] = 0.f;

    const size_t arow_base = (size_t)(by * 128 + lr) * DM;
    const size_t wrow = (size_t)(bx * 128 + lr) * D3;

    for (int c0 = 0; c0 < D3; c0 += 16) {
        const int seg = c0 >> 10;
        const float* Asrc = (seg == 0) ? Aq : ((seg == 1) ? Ak : Av);
        const int cl = (c0 & 1023) + lc;

        float4 a0 = *(const float4*)(Asrc + arow_base + cl);
        float4 a1 = *(const float4*)(Asrc + arow_base + cl + 4);
        float4 b0 = *(const float4*)(W + wrow + c0 + lc);
        float4 b1 = *(const float4*)(W + wrow + c0 + lc + 4);

        __syncthreads();
        As[lc + 0][lr] = a0.x; As[lc + 1][lr] = a0.y;
        As[lc + 2][lr] = a0.z; As[lc + 3][lr] = a0.w;
        As[lc + 4][lr] = a1.x; As[lc + 5][lr] = a1.y;
        As[lc + 6][lr] = a1.z; As[lc + 7][lr] = a1.w;
        Bs[lc + 0][lr] = b0.x; Bs[lc + 1][lr] = b0.y;
        Bs[lc + 2][lr] = b0.z; Bs[lc + 3][lr] = b0.w;
        Bs[lc + 4][lr] = b1.x; Bs[lc + 5][lr] = b1.y;
        Bs[lc + 6][lr] = b1.z; Bs[lc + 7][lr] = b1.w;
        __syncthreads();

#pragma unroll
        for (int kk = 0; kk < 16; ++kk) {
            float4 aL = *(const float4*)&As[kk][ty * 8];
            float4 aH = *(const float4*)&As[kk][ty * 8 + 4];
            float4 bL = *(const float4*)&Bs[kk][tx * 8];
            float4 bH = *(const float4*)&Bs[kk][tx * 8 + 4];
            float av[8] = {aL.x, aL.y, aL.z, aL.w, aH.x, aH.y, aH.z, aH.w};
            float bv[8] = {bL.x, bL.y, bL.z, bL.w, bH.x, bH.y, bH.z, bH.w};
#pragma unroll
            for (int i = 0; i < 8; ++i)
#pragma unroll
                for (int j = 0; j < 8; ++j)
                    acc[i][j] += av[i] * bv[j];
        }
    }

    const int ncol = bx * 128 + tx * 8;
    float4 bias0 = *(const float4*)(bias + ncol);
    float4 bias1 = *(const float4*)(bias + ncol + 4);
#pragma unroll
    for (int i = 0; i < 8; ++i) {
        const int m = by * 128 + ty * 8 + i;
        float4 o0, o1;
        o0.x = acc[i][0] + bias0.x; o0.y = acc[i][1] + bias0.y;
        o0.z = acc[i][2] + bias0.z; o0.w = acc[i][3] + bias0.w;
        o1.x = acc[i][4] + bias1.x; o1.y = acc[i][5] + bias1.y;
        o1.z = acc[i][6] + bias1.z; o1.w = acc[i][7] + bias1.w;
        *(float4*)(C + (size_t)m * D3 + ncol)     = o0;
        *(float4*)(C + (size_t)m * D3 + ncol + 4) = o1;
    }
}

// ---------------------------------------------------------------------------
// MFMA flash attention.
// Block = 4 waves, 128 q-rows of one (b,h); wave owns 32 rows (2 row-tiles).
// KV tiles of 64 staged in LDS: K hi/lo bf16 (row-major, chunk-XOR swizzle),
// V bf16 transposed Vt[d][k] (same swizzle). Scores = hiQ*hiK + hiQ*loK +
// loQ*hiK (fp32-class accuracy); P and V in plain bf16.
// mfma_f32_16x16x32_bf16 layouts:
//   A: lane l -> A[l&15][8*(l>>4)+e]   B: lane l -> B[8*(l>>4)+e][l&15]
//   C/D: lane l, reg r -> C[(l>>4)*4+r][l&15]
// P goes through per-wave LDS (no barrier) to re-layout C->A.
// ---------------------------------------------------------------------------
__global__ __launch_bounds__(256, 2) void attn_mfma_kernel(
    const float* __restrict__ qkv, float* __restrict__ attn)
{
    __shared__ unsigned short Khi[KVBLK * HD];       // 8 KB
    __shared__ unsigned short Klo[KVBLK * HD];       // 8 KB
    __shared__ unsigned short Vt [HD * KVBLK];       // 8 KB, [d][k]
    __shared__ unsigned short Plds[4 * 32 * KVBLK];  // 16 KB, per-wave [q][k]

    const int tid  = threadIdx.x;
    const int lane = tid & 63;
    const int wave = tid >> 6;
    const int l15  = lane & 15;
    const int lg   = lane >> 4;            // 0..3

    const int nq  = SEQ / QBLK;            // 16
    const int bid = blockIdx.x;
    const int b   = bid / (NH * nq);
    const int h   = (bid / nq) % NH;
    const int qc  = bid % nq;
    const int q0  = qc * QBLK + wave * 32;

    const float* qbase = qkv + ((size_t)(b * SEQ + q0)) * D3 + h * HD;
    const float* kbase = qkv + ((size_t)b * SEQ) * D3 + DM     + h * HD;
    const float* vbase = qkv + ((size_t)b * SEQ) * D3 + 2 * DM + h * HD;

    // ---- Q fragments (hi/lo), scale 1/8 folded in (exact) ----
    short8 qhi[2][2], qlo[2][2];
#pragma unroll
    for (int rt = 0; rt < 2; ++rt)
#pragma unroll
        for (int ks = 0; ks < 2; ++ks) {
            const float* p = qbase + (size_t)(rt * 16 + l15) * D3 + ks * 32 + 8 * lg;
            float4 x0 = *(const float4*)p;
            float4 x1 = *(const float4*)(p + 4);
            float xv[8] = {x0.x, x0.y, x0.z, x0.w, x1.x, x1.y, x1.z, x1.w};
            short8 hi, lo;
#pragma unroll
            for (int e = 0; e < 8; ++e) {
                float s = xv[e] * 0.125f;
                unsigned short hb = f2bf(s);
                hi[e] = (short)hb;
                lo[e] = (short)f2bf(s - bf2f(hb));
            }
            qhi[rt][ks] = hi; qlo[rt][ks] = lo;
        }

    f32x4 oacc[2][4];
#pragma unroll
    for (int rt = 0; rt < 2; ++rt)
#pragma unroll
        for (int dct = 0; dct < 4; ++dct) oacc[rt][dct] = (f32x4){0.f, 0.f, 0.f, 0.f};

    float mrun[2][4], lrun[2][4];
#pragma unroll
    for (int rt = 0; rt < 2; ++rt)
#pragma unroll
        for (int r = 0; r < 4; ++r) { mrun[rt][r] = -INFINITY; lrun[rt][r] = 0.f; }

    const int pbase = wave * 32 * KVBLK;

    for (int t = 0; t < SEQ / KVBLK; ++t) {
        __syncthreads();   // previous tile's LDS reads done

        // ---- stage K tile: hi/lo bf16, swizzled ----
#pragma unroll
        for (int ci = 0; ci < 2; ++ci) {
            const int cid = ci * 256 + tid;        // 0..511
            const int row = cid >> 3;              // 0..63
            const int c   = cid & 7;               // 8-col chunk
            const float* p = kbase + (size_t)(t * KVBLK + row) * D3 + c * 8;
            float4 x0 = *(const float4*)p;
            float4 x1 = *(const float4*)(p + 4);
            float xv[8] = {x0.x, x0.y, x0.z, x0.w, x1.x, x1.y, x1.z, x1.w};
            short8 hi, lo;
#pragma unroll
            for (int e = 0; e < 8; ++e) {
                unsigned short hb = f2bf(xv[e]);
                hi[e] = (short)hb;
                lo[e] = (short)f2bf(xv[e] - bf2f(hb));
            }
            const int cs = (c ^ (row & 7)) * 8;
            *(short8*)&Khi[row * HD + cs] = hi;
            *(short8*)&Klo[row * HD + cs] = lo;
        }
        // ---- stage V tile transposed: Vt[d][k] bf16, swizzled ----
#pragma unroll
        for (int i = 0; i < 4; ++i) {
            const int fid = i * 256 + tid;         // 0..1023
            const int k   = fid >> 4;              // 0..63
            const int c4  = fid & 15;              // float4 index along d
            const float* p = vbase + (size_t)(t * KVBLK + k) * D3 + c4 * 4;
            float4 x = *(const float4*)p;
            float xv[4] = {x.x, x.y, x.z, x.w};
#pragma unroll
            for (int e = 0; e < 4; ++e) {
                const int d = c4 * 4 + e;
                Vt[d * KVBLK + (((k >> 3) ^ (d & 7)) * 8) + (k & 7)] = f2bf(xv[e]);
            }
        }
        __syncthreads();

        // ---- QK^T: sc[rt][ct] = Q(32xHD) x K^T(HDx64), hi/lo 3-term ----
        f32x4 sc[2][4];
#pragma unroll
        for (int rt = 0; rt < 2; ++rt)
#pragma unroll
            for (int ct = 0; ct < 4; ++ct) sc[rt][ct] = (f32x4){0.f, 0.f, 0.f, 0.f};

#pragma unroll
        for (int ct = 0; ct < 4; ++ct) {
            const int krow = ct * 16 + l15;
#pragma unroll
            for (int ks = 0; ks < 2; ++ks) {
                const int cs = ((ks * 4 + lg) ^ (krow & 7)) * 8;
                short8 khi = *(short8*)&Khi[krow * HD + cs];
                short8 klo = *(short8*)&Klo[krow * HD + cs];
#pragma unroll
                for (int rt = 0; rt < 2; ++rt) {
                    sc[rt][ct] = __builtin_amdgcn_mfma_f32_16x16x32_bf16(qhi[rt][ks], khi, sc[rt][ct], 0, 0, 0);
                    sc[rt][ct] = __builtin_amdgcn_mfma_f32_16x16x32_bf16(qhi[rt][ks], klo, sc[rt][ct], 0, 0, 0);
                    sc[rt][ct] = __builtin_amdgcn_mfma_f32_16x16x32_bf16(qlo[rt][ks], khi, sc[rt][ct], 0, 0, 0);
                }
            }
        }

        // ---- online softmax (rows spread: row=(l>>4)*4+r, col=l&15) ----
#pragma unroll
        for (int rt = 0; rt < 2; ++rt) {
            float mt[4];
#pragma unroll
            for (int r = 0; r < 4; ++r)
                mt[r] = fmaxf(fmaxf(sc[rt][0][r], sc[rt][1][r]),
                              fmaxf(sc[rt][2][r], sc[rt][3][r]));
#pragma unroll
            for (int m = 1; m < 16; m <<= 1)
#pragma unroll
                for (int r = 0; r < 4; ++r)
                    mt[r] = fmaxf(mt[r], __shfl_xor(mt[r], m));

            float alpha[4], mn[4];
#pragma unroll
            for (int r = 0; r < 4; ++r) {
                mn[r] = fmaxf(mrun[rt][r], mt[r]);
                alpha[r] = __expf(mrun[rt][r] - mn[r]);
                mrun[rt][r] = mn[r];
            }
            float ls[4] = {0.f, 0.f, 0.f, 0.f};
#pragma unroll
            for (int ct = 0; ct < 4; ++ct) {
                f32x4 v = sc[rt][ct];
#pragma unroll
                for (int r = 0; r < 4; ++r) {
                    v[r] = __expf(v[r] - mn[r]);
                    ls[r] += v[r];
                    const int q = rt * 16 + lg * 4 + r;
                    const int k = ct * 16 + l15;
                    Plds[pbase + q * KVBLK + (((k >> 3) ^ (q & 7)) * 8) + (k & 7)] = f2bf(v[r]);
                }
            }
#pragma unroll
            for (int m = 1; m < 16; m <<= 1)
#pragma unroll
                for (int r = 0; r < 4; ++r) ls[r] += __shfl_xor(ls[r], m);
#pragma unroll
            for (int r = 0; r < 4; ++r) lrun[rt][r] = lrun[rt][r] * alpha[r] + ls[r];
#pragma unroll
            for (int dct = 0; dct < 4; ++dct)
#pragma unroll
                for (int r = 0; r < 4; ++r) oacc[rt][dct][r] *= alpha[r];
        }

        // ---- PV: O += P(32x64) x V(64x64); P from per-wave LDS ----
#pragma unroll
        for (int ks2 = 0; ks2 < 2; ++ks2) {
            short8 pa[2];
#pragma unroll
            for (int rt = 0; rt < 2; ++rt) {
                const int q = rt * 16 + l15;
                pa[rt] = *(short8*)&Plds[pbase + q * KVBLK + (((ks2 * 4 + lg) ^ (q & 7)) * 8)];
            }
#pragma unroll
            for (int dct = 0; dct < 4; ++dct) {
                const int d = dct * 16 + l15;
                short8 vf = *(short8*)&Vt[d * KVBLK + (((ks2 * 4 + lg) ^ (d & 7)) * 8)];
#pragma unroll
                for (int rt = 0; rt < 2; ++rt)
                    oacc[rt][dct] = __builtin_amdgcn_mfma_f32_16x16x32_bf16(pa[rt], vf, oacc[rt][dct], 0, 0, 0);
            }
        }
    }

    // ---- epilogue: O/l -> attn (combine-heads layout) ----
#pragma unroll
    for (int rt = 0; rt < 2; ++rt) {
        float inv[4];
#pragma unroll
        for (int r = 0; r < 4; ++r) inv[r] = 1.f / lrun[rt][r];
#pragma unroll
        for (int dct = 0; dct < 4; ++dct)
#pragma unroll
            for (int r = 0; r < 4; ++r) {
                const int q = q0 + rt * 16 + lg * 4 + r;
                attn[(size_t)(b * SEQ + q) * DM + h * HD + dct * 16 + l15] =
                    oacc[rt][dct][r] * inv[r];
            }
    }
}

// ---------------------------------------------------------------------------
extern "C" void kernel_launch(void* const* d_in, const int* in_sizes, int n_in,
                              void* d_out, int out_size, void* d_ws, size_t ws_size,
                              hipStream_t stream) {
    const float* q    = (const float*)d_in[0];
    const float* k    = (const float*)d_in[1];
    const float* v    = (const float*)d_in[2];
    const float* Wqkv = (const float*)d_in[3];
    const float* bqkv = (const float*)d_in[4];
    const float* Wo   = (const float*)d_in[5];
    const float* bo   = (const float*)d_in[6];
    float* out = (float*)d_out;

    float* qkv  = (float*)d_ws;                       // [4096][3072] fp32
    float* attn = qkv + (size_t)MROWS * D3;           // [4096][1024] fp32

    // 1) QKV projection
    {
        dim3 grid(D3 / 128, MROWS / 128);             // 24 x 32
        qkv_gemm_kernel<<<grid, 256, 0, stream>>>(q, k, v, Wqkv, bqkv, qkv);
    }
    // 2) attention (MFMA flash)
    {
        dim3 grid(BS * NH * (SEQ / QBLK));            // 512
        attn_mfma_kernel<<<grid, 256, 0, stream>>>(qkv, attn);
    }
    // 3) output projection
    {
        dim3 grid(DM / 128, MROWS / 128);             // 8 x 32
        gemm_bias_kernel<DM, DM><<<grid, 256, 0, stream>>>(attn, Wo, bo, out);
    }
}

// Round 3
// 267.527 us; speedup vs baseline: 17.1041x; 4.6126x over previous
//
#include <hip/hip_runtime.h>
#include <cmath>

#define BS   2
#define SEQ  2048
#define DM   1024
#define NH   16
#define HD   64
#define D3   3072
#define MROWS 4096
#define KVBLK 64
#define QBLK  128

typedef _Float16 f16;
typedef __attribute__((ext_vector_type(4))) _Float16 half4;
typedef __attribute__((ext_vector_type(8))) _Float16 half8;
typedef __attribute__((ext_vector_type(4))) float f32x4;
typedef unsigned int u32;

__device__ __forceinline__ void async_cp16(const void* g, void* s) {
    __builtin_amdgcn_global_load_lds(
        (const __attribute__((address_space(1))) u32*)g,
        (__attribute__((address_space(3))) u32*)s, 16, 0, 0);
}

// ---------------------------------------------------------------------------
// Conversion passes (memory-bound, trivial)
// ---------------------------------------------------------------------------
// concat(q,k,v) fp32 [4096][1024]x3 -> A fp16 [4096][3072]
__global__ __launch_bounds__(256) void conv_concat_kernel(
    const float* __restrict__ q, const float* __restrict__ k,
    const float* __restrict__ v, f16* __restrict__ out)
{
    const int seg = blockIdx.x;            // 0..2
    const int row = blockIdx.y;            // 0..4095
    const int c   = threadIdx.x * 4;
    const float* src = (seg == 0 ? q : (seg == 1 ? k : v)) + (size_t)row * DM + c;
    float4 x = *(const float4*)src;
    half4 h = {(f16)x.x, (f16)x.y, (f16)x.z, (f16)x.w};
    *(half4*)&out[(size_t)row * D3 + seg * DM + c] = h;
}

__global__ __launch_bounds__(256) void conv_plain_kernel(
    const float* __restrict__ src, f16* __restrict__ dst, int n4)
{
    int i = blockIdx.x * 256 + threadIdx.x;
    const int stride = gridDim.x * 256;
    for (; i < n4; i += stride) {
        float4 x = *(const float4*)&src[(size_t)i * 4];
        half4 h = {(f16)x.x, (f16)x.y, (f16)x.z, (f16)x.w};
        *(half4*)&dst[(size_t)i * 4] = h;
    }
}

// ---------------------------------------------------------------------------
// fp16 MFMA GEMM: C[M][NDIM] = A[M][KDIM](f16) @ W[NDIM][KDIM](f16)^T + bias
// m97 structure: 128x128 tile, BK=32, 4 waves (each 64x64 = 4x4 16x16 frags),
// global_load_lds width-16 staging (linear LDS dest), source-XOR swizzle
// chunk ^= ((row>>1)&3) applied at global source AND ds_read (rule #21).
// Per K-step: 16 MFMA + 8 ds_read_b128 + 4 global_load_lds_dwordx4.
// ---------------------------------------------------------------------------
template<int KDIM, int NDIM, bool F16OUT>
__global__ __launch_bounds__(256) void gemm_f16_kernel(
    const f16* __restrict__ A, const f16* __restrict__ W,
    const float* __restrict__ bias, void* __restrict__ Cout)
{
    __shared__ f16 As[128 * 32];
    __shared__ f16 Ws[128 * 32];

    const int tid  = threadIdx.x;
    const int lane = tid & 63;
    const int wave = tid >> 6;
    const int l15  = lane & 15;
    const int lg   = lane >> 4;           // 0..3
    const int wm   = wave >> 1;           // 0..1
    const int wn   = wave & 1;            // 0..1

    // XCD-aware bijective swizzle (gridDim.x % 8 == 0 for both instantiations)
    const int cpx = gridDim.x >> 3;
    const int lid = (blockIdx.x & 7) * cpx + (blockIdx.x >> 3);
    const int NT  = NDIM / 128;
    const int tM0 = (lid / NT) * 128;
    const int tN0 = (lid % NT) * 128;

    // staging: per instruction 64 lanes cover 16 rows x 64B; lane -> (row,chunk)
    const int srow = lane >> 2;           // 0..15
    const int sch  = lane & 3;
    const int ssc  = sch ^ ((srow >> 1) & 3);   // swizzled source chunk

    const f16* gA0 = A + (size_t)(tM0 + wave * 32      + srow) * KDIM + ssc * 8;
    const f16* gA1 = A + (size_t)(tM0 + wave * 32 + 16 + srow) * KDIM + ssc * 8;
    const f16* gW0 = W + (size_t)(tN0 + wave * 32      + srow) * KDIM + ssc * 8;
    const f16* gW1 = W + (size_t)(tN0 + wave * 32 + 16 + srow) * KDIM + ssc * 8;
    f16* lA0 = &As[(wave * 32)      * 32];
    f16* lA1 = &As[(wave * 32 + 16) * 32];
    f16* lW0 = &Ws[(wave * 32)      * 32];
    f16* lW1 = &Ws[(wave * 32 + 16) * 32];

    f32x4 acc[4][4];
#pragma unroll
    for (int i = 0; i < 4; ++i)
#pragma unroll
        for (int j = 0; j < 4; ++j) acc[i][j] = (f32x4){0.f, 0.f, 0.f, 0.f};

    // fragment ds_read offsets (swizzled chunk)
    const int fsw = (lg ^ ((l15 >> 1) & 3)) * 8;
    int aoff[4], woff[4];
#pragma unroll
    for (int mi = 0; mi < 4; ++mi) aoff[mi] = (wm * 64 + mi * 16 + l15) * 32 + fsw;
#pragma unroll
    for (int ni = 0; ni < 4; ++ni) woff[ni] = (wn * 64 + ni * 16 + l15) * 32 + fsw;

    for (int k0 = 0; k0 < KDIM; k0 += 32) {
        __syncthreads();                  // previous iteration's reads done
        async_cp16(gA0 + k0, lA0);
        async_cp16(gA1 + k0, lA1);
        async_cp16(gW0 + k0, lW0);
        async_cp16(gW1 + k0, lW1);
        __syncthreads();                  // vmcnt(0) drain + barrier

        half8 af[4], wf[4];
#pragma unroll
        for (int mi = 0; mi < 4; ++mi) af[mi] = *(half8*)&As[aoff[mi]];
#pragma unroll
        for (int ni = 0; ni < 4; ++ni) wf[ni] = *(half8*)&Ws[woff[ni]];
#pragma unroll
        for (int mi = 0; mi < 4; ++mi)
#pragma unroll
            for (int ni = 0; ni < 4; ++ni)
                acc[mi][ni] = __builtin_amdgcn_mfma_f32_16x16x32_f16(
                    af[mi], wf[ni], acc[mi][ni], 0, 0, 0);
    }

    float bv[4];
#pragma unroll
    for (int ni = 0; ni < 4; ++ni) bv[ni] = bias[tN0 + wn * 64 + ni * 16 + l15];

#pragma unroll
    for (int mi = 0; mi < 4; ++mi)
#pragma unroll
        for (int ni = 0; ni < 4; ++ni)
#pragma unroll
            for (int r = 0; r < 4; ++r) {
                const int m   = tM0 + wm * 64 + mi * 16 + lg * 4 + r;
                const int col = tN0 + wn * 64 + ni * 16 + l15;
                const float val = acc[mi][ni][r] + bv[ni];
                if constexpr (F16OUT)
                    ((f16*)Cout)[(size_t)m * NDIM + col] = (f16)val;
                else
                    ((float*)Cout)[(size_t)m * NDIM + col] = val;
            }
}

// ---------------------------------------------------------------------------
// fp16 MFMA flash attention (round-2 structure, single-term f16 QK^T).
// Reads qkv f16 [4096][3072] (bias included), writes attn f16 [4096][1024].
// Scale 1/8 applied to scores post-MFMA (exact).
// ---------------------------------------------------------------------------
__global__ __launch_bounds__(256, 2) void attn_mfma_kernel(
    const f16* __restrict__ qkvh, f16* __restrict__ attnh)
{
    __shared__ f16 Kh[KVBLK * HD];        // 8 KB
    __shared__ f16 Vt[HD * KVBLK];        // 8 KB, [d][k]
    __shared__ f16 Pl[4 * 32 * KVBLK];    // 16 KB, per-wave [q][k]

    const int tid  = threadIdx.x;
    const int lane = tid & 63;
    const int wave = tid >> 6;
    const int l15  = lane & 15;
    const int lg   = lane >> 4;

    const int nq  = SEQ / QBLK;           // 16
    const int bid = blockIdx.x;
    const int b   = bid / (NH * nq);
    const int h   = (bid / nq) % NH;
    const int qc  = bid % nq;
    const int q0  = qc * QBLK + wave * 32;
    const size_t bS = (size_t)b * SEQ;

    // Q fragments: [2 row-tiles][2 k-slices]
    half8 qf[2][2];
#pragma unroll
    for (int rt = 0; rt < 2; ++rt)
#pragma unroll
        for (int ks = 0; ks < 2; ++ks)
            qf[rt][ks] = *(const half8*)&qkvh[(bS + q0 + rt * 16 + l15) * D3 +
                                              h * HD + ks * 32 + lg * 8];

    f32x4 oacc[2][4];
#pragma unroll
    for (int rt = 0; rt < 2; ++rt)
#pragma unroll
        for (int dct = 0; dct < 4; ++dct) oacc[rt][dct] = (f32x4){0.f, 0.f, 0.f, 0.f};

    float mrun[2][4], lrun[2][4];
#pragma unroll
    for (int rt = 0; rt < 2; ++rt)
#pragma unroll
        for (int r = 0; r < 4; ++r) { mrun[rt][r] = -INFINITY; lrun[rt][r] = 0.f; }

    const int pbase = wave * 32 * KVBLK;

    for (int t = 0; t < SEQ / KVBLK; ++t) {
        __syncthreads();

        // stage K tile [64][64] f16, chunk-XOR swizzle
#pragma unroll
        for (int ci = 0; ci < 2; ++ci) {
            const int cid = ci * 256 + tid;       // 0..511
            const int row = cid >> 3;             // 0..63
            const int c   = cid & 7;              // 16B chunk
            half8 kv = *(const half8*)&qkvh[(bS + t * KVBLK + row) * D3 +
                                            DM + h * HD + c * 8];
            *(half8*)&Kh[row * HD + ((c ^ (row & 7)) * 8)] = kv;
        }
        // stage V transposed Vt[d][k], swizzled
#pragma unroll
        for (int ci = 0; ci < 2; ++ci) {
            const int cid = ci * 256 + tid;
            const int k   = cid >> 3;             // 0..63
            const int c   = cid & 7;
            half8 vv = *(const half8*)&qkvh[(bS + t * KVBLK + k) * D3 +
                                            2 * DM + h * HD + c * 8];
#pragma unroll
            for (int e = 0; e < 8; ++e) {
                const int d = c * 8 + e;
                Vt[d * KVBLK + (((k >> 3) ^ (d & 7)) * 8) + (k & 7)] = vv[e];
            }
        }
        __syncthreads();

        // QK^T
        f32x4 sc[2][4];
#pragma unroll
        for (int rt = 0; rt < 2; ++rt)
#pragma unroll
            for (int ct = 0; ct < 4; ++ct) sc[rt][ct] = (f32x4){0.f, 0.f, 0.f, 0.f};

#pragma unroll
        for (int ct = 0; ct < 4; ++ct) {
            const int krow = ct * 16 + l15;
#pragma unroll
            for (int ks = 0; ks < 2; ++ks) {
                half8 kf = *(half8*)&Kh[krow * HD + (((ks * 4 + lg) ^ (krow & 7)) * 8)];
#pragma unroll
                for (int rt = 0; rt < 2; ++rt)
                    sc[rt][ct] = __builtin_amdgcn_mfma_f32_16x16x32_f16(
                        qf[rt][ks], kf, sc[rt][ct], 0, 0, 0);
            }
        }
        // scale 1/sqrt(64)
#pragma unroll
        for (int rt = 0; rt < 2; ++rt)
#pragma unroll
            for (int ct = 0; ct < 4; ++ct)
#pragma unroll
                for (int r = 0; r < 4; ++r) sc[rt][ct][r] *= 0.125f;

        // online softmax; P -> per-wave LDS (f16)
#pragma unroll
        for (int rt = 0; rt < 2; ++rt) {
            float mt[4];
#pragma unroll
            for (int r = 0; r < 4; ++r)
                mt[r] = fmaxf(fmaxf(sc[rt][0][r], sc[rt][1][r]),
                              fmaxf(sc[rt][2][r], sc[rt][3][r]));
#pragma unroll
            for (int m = 1; m < 16; m <<= 1)
#pragma unroll
                for (int r = 0; r < 4; ++r)
                    mt[r] = fmaxf(mt[r], __shfl_xor(mt[r], m));

            float alpha[4], mn[4];
#pragma unroll
            for (int r = 0; r < 4; ++r) {
                mn[r] = fmaxf(mrun[rt][r], mt[r]);
                alpha[r] = __expf(mrun[rt][r] - mn[r]);
                mrun[rt][r] = mn[r];
            }
            float ls[4] = {0.f, 0.f, 0.f, 0.f};
#pragma unroll
            for (int ct = 0; ct < 4; ++ct) {
                f32x4 v = sc[rt][ct];
#pragma unroll
                for (int r = 0; r < 4; ++r) {
                    v[r] = __expf(v[r] - mn[r]);
                    ls[r] += v[r];
                    const int qq = rt * 16 + lg * 4 + r;
                    const int kk = ct * 16 + l15;
                    Pl[pbase + qq * KVBLK + (((kk >> 3) ^ (qq & 7)) * 8) + (kk & 7)] =
                        (f16)v[r];
                }
            }
#pragma unroll
            for (int m = 1; m < 16; m <<= 1)
#pragma unroll
                for (int r = 0; r < 4; ++r) ls[r] += __shfl_xor(ls[r], m);
#pragma unroll
            for (int r = 0; r < 4; ++r) lrun[rt][r] = lrun[rt][r] * alpha[r] + ls[r];
#pragma unroll
            for (int dct = 0; dct < 4; ++dct)
#pragma unroll
                for (int r = 0; r < 4; ++r) oacc[rt][dct][r] *= alpha[r];
        }

        // PV
#pragma unroll
        for (int ks2 = 0; ks2 < 2; ++ks2) {
            half8 pa[2];
#pragma unroll
            for (int rt = 0; rt < 2; ++rt) {
                const int qq = rt * 16 + l15;
                pa[rt] = *(half8*)&Pl[pbase + qq * KVBLK + (((ks2 * 4 + lg) ^ (qq & 7)) * 8)];
            }
#pragma unroll
            for (int dct = 0; dct < 4; ++dct) {
                const int d = dct * 16 + l15;
                half8 vf = *(half8*)&Vt[d * KVBLK + (((ks2 * 4 + lg) ^ (d & 7)) * 8)];
#pragma unroll
                for (int rt = 0; rt < 2; ++rt)
                    oacc[rt][dct] = __builtin_amdgcn_mfma_f32_16x16x32_f16(
                        pa[rt], vf, oacc[rt][dct], 0, 0, 0);
            }
        }
    }

    // epilogue: write attn f16 (combine-heads layout)
#pragma unroll
    for (int rt = 0; rt < 2; ++rt) {
        float inv[4];
#pragma unroll
        for (int r = 0; r < 4; ++r) inv[r] = 1.f / lrun[rt][r];
#pragma unroll
        for (int dct = 0; dct < 4; ++dct)
#pragma unroll
            for (int r = 0; r < 4; ++r) {
                const int qq = q0 + rt * 16 + lg * 4 + r;
                attnh[(bS + qq) * DM + h * HD + dct * 16 + l15] =
                    (f16)(oacc[rt][dct][r] * inv[r]);
            }
    }
}

// ---------------------------------------------------------------------------
extern "C" void kernel_launch(void* const* d_in, const int* in_sizes, int n_in,
                              void* d_out, int out_size, void* d_ws, size_t ws_size,
                              hipStream_t stream) {
    const float* q    = (const float*)d_in[0];
    const float* k    = (const float*)d_in[1];
    const float* v    = (const float*)d_in[2];
    const float* Wqkv = (const float*)d_in[3];
    const float* bqkv = (const float*)d_in[4];
    const float* Wo   = (const float*)d_in[5];
    const float* bo   = (const float*)d_in[6];
    float* out = (float*)d_out;

    // ws layout (bytes); attn/Wo reuse the Ain region after qkv_gemm is done
    // (stream-ordered). Peak = 69.2 MB.
    char* ws = (char*)d_ws;
    f16* Ain    = (f16*)ws;                        // [4096][3072] 25.2 MB
    f16* attn_h = (f16*)ws;                        // [4096][1024] 8.4 MB (reuse)
    f16* Wo_h   = (f16*)(ws + 16777216);           // [1024][1024] 2.1 MB (reuse)
    f16* Wqkv_h = (f16*)(ws + 25165824);           // [3072][3072] 18.9 MB
    f16* qkv_h  = (f16*)(ws + 44040192);           // [4096][3072] 25.2 MB

    // 1) convert inputs (concat) + Wqkv to f16
    conv_concat_kernel<<<dim3(3, MROWS), 256, 0, stream>>>(q, k, v, Ain);
    conv_plain_kernel<<<2048, 256, 0, stream>>>(Wqkv, Wqkv_h, D3 * D3 / 4);

    // 2) QKV projection (f16 MFMA), writes qkv f16 with bias
    gemm_f16_kernel<D3, D3, true><<<dim3((MROWS / 128) * (D3 / 128)), 256, 0, stream>>>(
        Ain, Wqkv_h, bqkv, qkv_h);

    // 3) attention (f16 MFMA flash), writes attn f16
    attn_mfma_kernel<<<dim3(BS * NH * (SEQ / QBLK)), 256, 0, stream>>>(qkv_h, attn_h);

    // 4) convert Wo (after qkv_gemm: region overlaps Ain)
    conv_plain_kernel<<<512, 256, 0, stream>>>(Wo, Wo_h, DM * DM / 4);

    // 5) output projection (f16 MFMA), fp32 out
    gemm_f16_kernel<DM, DM, false><<<dim3((MROWS / 128) * (DM / 128)), 256, 0, stream>>>(
        attn_h, Wo_h, bo, out);
}

// Round 4
// 242.915 us; speedup vs baseline: 18.8371x; 1.1013x over previous
//
#include <hip/hip_runtime.h>
#include <cmath>

#define BS   2
#define SEQ  2048
#define DM   1024
#define NH   16
#define HD   64
#define D3   3072
#define MROWS 4096
#define KVBLK 64
#define QBLK  128
#define NTILES (SEQ / KVBLK)   // 32

typedef _Float16 f16;
typedef __attribute__((ext_vector_type(4))) _Float16 half4;
typedef __attribute__((ext_vector_type(8))) _Float16 half8;
typedef __attribute__((ext_vector_type(4))) float f32x4;
typedef unsigned int u32;
typedef __attribute__((ext_vector_type(4))) u32 u32x4;

__device__ __forceinline__ void async_cp16(const void* g, void* s) {
    __builtin_amdgcn_global_load_lds(
        (const __attribute__((address_space(1))) u32*)g,
        (__attribute__((address_space(3))) u32*)s, 16, 0, 0);
}

// ---------------------------------------------------------------------------
// Conversion passes
// ---------------------------------------------------------------------------
__global__ __launch_bounds__(256) void conv_concat_kernel(
    const float* __restrict__ q, const float* __restrict__ k,
    const float* __restrict__ v, f16* __restrict__ out)
{
    const int seg = blockIdx.x;            // 0..2
    const int row = blockIdx.y;            // 0..4095
    const int c   = threadIdx.x * 4;
    const float* src = (seg == 0 ? q : (seg == 1 ? k : v)) + (size_t)row * DM + c;
    float4 x = *(const float4*)src;
    half4 h = {(f16)x.x, (f16)x.y, (f16)x.z, (f16)x.w};
    *(half4*)&out[(size_t)row * D3 + seg * DM + c] = h;
}

__global__ __launch_bounds__(256) void conv_plain_kernel(
    const float* __restrict__ src, f16* __restrict__ dst, int n4)
{
    int i = blockIdx.x * 256 + threadIdx.x;
    const int stride = gridDim.x * 256;
    for (; i < n4; i += stride) {
        float4 x = *(const float4*)&src[(size_t)i * 4];
        half4 h = {(f16)x.x, (f16)x.y, (f16)x.z, (f16)x.w};
        *(half4*)&dst[(size_t)i * 4] = h;
    }
}

// ---------------------------------------------------------------------------
// fp16 MFMA GEMM (m97 structure) — unchanged from round 3
// ---------------------------------------------------------------------------
template<int KDIM, int NDIM, bool F16OUT>
__global__ __launch_bounds__(256) void gemm_f16_kernel(
    const f16* __restrict__ A, const f16* __restrict__ W,
    const float* __restrict__ bias, void* __restrict__ Cout)
{
    __shared__ f16 As[128 * 32];
    __shared__ f16 Ws[128 * 32];

    const int tid  = threadIdx.x;
    const int lane = tid & 63;
    const int wave = tid >> 6;
    const int l15  = lane & 15;
    const int lg   = lane >> 4;
    const int wm   = wave >> 1;
    const int wn   = wave & 1;

    const int cpx = gridDim.x >> 3;
    const int lid = (blockIdx.x & 7) * cpx + (blockIdx.x >> 3);
    const int NT  = NDIM / 128;
    const int tM0 = (lid / NT) * 128;
    const int tN0 = (lid % NT) * 128;

    const int srow = lane >> 2;
    const int sch  = lane & 3;
    const int ssc  = sch ^ ((srow >> 1) & 3);

    const f16* gA0 = A + (size_t)(tM0 + wave * 32      + srow) * KDIM + ssc * 8;
    const f16* gA1 = A + (size_t)(tM0 + wave * 32 + 16 + srow) * KDIM + ssc * 8;
    const f16* gW0 = W + (size_t)(tN0 + wave * 32      + srow) * KDIM + ssc * 8;
    const f16* gW1 = W + (size_t)(tN0 + wave * 32 + 16 + srow) * KDIM + ssc * 8;
    f16* lA0 = &As[(wave * 32)      * 32];
    f16* lA1 = &As[(wave * 32 + 16) * 32];
    f16* lW0 = &Ws[(wave * 32)      * 32];
    f16* lW1 = &Ws[(wave * 32 + 16) * 32];

    f32x4 acc[4][4];
#pragma unroll
    for (int i = 0; i < 4; ++i)
#pragma unroll
        for (int j = 0; j < 4; ++j) acc[i][j] = (f32x4){0.f, 0.f, 0.f, 0.f};

    const int fsw = (lg ^ ((l15 >> 1) & 3)) * 8;
    int aoff[4], woff[4];
#pragma unroll
    for (int mi = 0; mi < 4; ++mi) aoff[mi] = (wm * 64 + mi * 16 + l15) * 32 + fsw;
#pragma unroll
    for (int ni = 0; ni < 4; ++ni) woff[ni] = (wn * 64 + ni * 16 + l15) * 32 + fsw;

    for (int k0 = 0; k0 < KDIM; k0 += 32) {
        __syncthreads();
        async_cp16(gA0 + k0, lA0);
        async_cp16(gA1 + k0, lA1);
        async_cp16(gW0 + k0, lW0);
        async_cp16(gW1 + k0, lW1);
        __syncthreads();

        half8 af[4], wf[4];
#pragma unroll
        for (int mi = 0; mi < 4; ++mi) af[mi] = *(half8*)&As[aoff[mi]];
#pragma unroll
        for (int ni = 0; ni < 4; ++ni) wf[ni] = *(half8*)&Ws[woff[ni]];
#pragma unroll
        for (int mi = 0; mi < 4; ++mi)
#pragma unroll
            for (int ni = 0; ni < 4; ++ni)
                acc[mi][ni] = __builtin_amdgcn_mfma_f32_16x16x32_f16(
                    af[mi], wf[ni], acc[mi][ni], 0, 0, 0);
    }

    float bv[4];
#pragma unroll
    for (int ni = 0; ni < 4; ++ni) bv[ni] = bias[tN0 + wn * 64 + ni * 16 + l15];

#pragma unroll
    for (int mi = 0; mi < 4; ++mi)
#pragma unroll
        for (int ni = 0; ni < 4; ++ni)
#pragma unroll
            for (int r = 0; r < 4; ++r) {
                const int m   = tM0 + wm * 64 + mi * 16 + lg * 4 + r;
                const int col = tN0 + wn * 64 + ni * 16 + l15;
                const float val = acc[mi][ni][r] + bv[ni];
                if constexpr (F16OUT)
                    ((f16*)Cout)[(size_t)m * NDIM + col] = (f16)val;
                else
                    ((float*)Cout)[(size_t)m * NDIM + col] = val;
            }
}

// ---------------------------------------------------------------------------
// fp16 MFMA flash attention, pipelined:
//  - K staged via global_load_lds (linear LDS dest, source-chunk XOR swizzle)
//  - V loaded to regs early, v_perm pair-pack transposed into Vt after PV
//  - double-buffered K/V (distinct static arrays, 2x-unrolled), 1 barrier/tile
//  - P-store swizzle chunk=(k>>3)^(lg<<1): 2 lanes/bank on store
// ---------------------------------------------------------------------------

// transpose-store 2 k-rows x 8 d into VtN, swizzle chunk ^= (d&7)^(d>>3)
#define V_STORE(VtN, va, vb) do {                                             \
    u32x4 aw_ = __builtin_bit_cast(u32x4, va);                                \
    u32x4 bw_ = __builtin_bit_cast(u32x4, vb);                                \
    _Pragma("unroll")                                                         \
    for (int wd_ = 0; wd_ < 4; ++wd_) {                                       \
        u32 lo_ = __builtin_amdgcn_perm(bw_[wd_], aw_[wd_], 0x05040100u);     \
        u32 hi_ = __builtin_amdgcn_perm(bw_[wd_], aw_[wd_], 0x07060302u);     \
        const int dl_ = vd0 + 2 * wd_;                                        \
        const int dh_ = dl_ + 1;                                              \
        *(u32*)&VtN[dl_ * KVBLK + (((vp >> 2) ^ (dl_ & 7) ^ (dl_ >> 3)) * 8)  \
                    + 2 * (vp & 3)] = lo_;                                    \
        *(u32*)&VtN[dh_ * KVBLK + (((vp >> 2) ^ (dh_ & 7) ^ (dh_ >> 3)) * 8)  \
                    + 2 * (vp & 3)] = hi_;                                    \
    }                                                                         \
} while (0)

#define ATTN_STEP(KhC, VtC, KhN, VtN, TT, PF) do {                            \
    half8 va_ = {}, vb_ = {};                                                 \
    if (PF) {                                                                 \
        const size_t nro_ = (size_t)((TT) + 1) * KVBLK;                       \
        async_cp16(kxsrc + (nro_ + wave * 16 +     krow_l) * D3,              \
                   &KhN[(wave * 16) * HD]);                                   \
        async_cp16(kxsrc + (nro_ + wave * 16 + 8 + krow_l) * D3,              \
                   &KhN[(wave * 16 + 8) * HD]);                               \
        va_ = *(const half8*)(vsrc0 + nro_ * D3);                             \
        vb_ = *(const half8*)(vsrc0 + nro_ * D3 + D3);                        \
    }                                                                         \
    f32x4 sc[2][4];                                                           \
    _Pragma("unroll")                                                         \
    for (int rt = 0; rt < 2; ++rt)                                            \
        _Pragma("unroll")                                                     \
        for (int ct = 0; ct < 4; ++ct) sc[rt][ct] = (f32x4){0.f,0.f,0.f,0.f}; \
    __builtin_amdgcn_s_setprio(1);                                            \
    _Pragma("unroll")                                                         \
    for (int ct = 0; ct < 4; ++ct) {                                          \
        const int krow = ct * 16 + l15;                                       \
        _Pragma("unroll")                                                     \
        for (int ks = 0; ks < 2; ++ks) {                                      \
            half8 kf = *(half8*)&KhC[krow * HD +                              \
                                     (((ks * 4 + lg) ^ (krow & 7)) * 8)];     \
            _Pragma("unroll")                                                 \
            for (int rt = 0; rt < 2; ++rt)                                    \
                sc[rt][ct] = __builtin_amdgcn_mfma_f32_16x16x32_f16(          \
                    qf[rt][ks], kf, sc[rt][ct], 0, 0, 0);                     \
        }                                                                     \
    }                                                                         \
    __builtin_amdgcn_s_setprio(0);                                            \
    _Pragma("unroll")                                                         \
    for (int rt = 0; rt < 2; ++rt)                                            \
        _Pragma("unroll")                                                     \
        for (int ct = 0; ct < 4; ++ct)                                        \
            _Pragma("unroll")                                                 \
            for (int r = 0; r < 4; ++r) sc[rt][ct][r] *= 0.125f;              \
    _Pragma("unroll")                                                         \
    for (int rt = 0; rt < 2; ++rt) {                                          \
        float mt[4];                                                          \
        _Pragma("unroll")                                                     \
        for (int r = 0; r < 4; ++r)                                           \
            mt[r] = fmaxf(fmaxf(sc[rt][0][r], sc[rt][1][r]),                  \
                          fmaxf(sc[rt][2][r], sc[rt][3][r]));                 \
        _Pragma("unroll")                                                     \
        for (int m = 1; m < 16; m <<= 1)                                      \
            _Pragma("unroll")                                                 \
            for (int r = 0; r < 4; ++r)                                       \
                mt[r] = fmaxf(mt[r], __shfl_xor(mt[r], m));                   \
        float alpha[4], mn[4];                                                \
        _Pragma("unroll")                                                     \
        for (int r = 0; r < 4; ++r) {                                         \
            mn[r] = fmaxf(mrun[rt][r], mt[r]);                                \
            alpha[r] = __expf(mrun[rt][r] - mn[r]);                           \
            mrun[rt][r] = mn[r];                                              \
        }                                                                     \
        float ls[4] = {0.f, 0.f, 0.f, 0.f};                                   \
        _Pragma("unroll")                                                     \
        for (int ct = 0; ct < 4; ++ct) {                                      \
            f32x4 v = sc[rt][ct];                                             \
            _Pragma("unroll")                                                 \
            for (int r = 0; r < 4; ++r) {                                     \
                v[r] = __expf(v[r] - mn[r]);                                  \
                ls[r] += v[r];                                                \
                const int qq = rt * 16 + lg * 4 + r;                          \
                const int chP = (ct * 2 + (l15 >> 3)) ^ (lg << 1);            \
                Pl[pbase + qq * KVBLK + chP * 8 + (l15 & 7)] = (f16)v[r];     \
            }                                                                 \
        }                                                                     \
        _Pragma("unroll")                                                     \
        for (int m = 1; m < 16; m <<= 1)                                      \
            _Pragma("unroll")                                                 \
            for (int r = 0; r < 4; ++r) ls[r] += __shfl_xor(ls[r], m);        \
        _Pragma("unroll")                                                     \
        for (int r = 0; r < 4; ++r)                                           \
            lrun[rt][r] = lrun[rt][r] * alpha[r] + ls[r];                     \
        _Pragma("unroll")                                                     \
        for (int dct = 0; dct < 4; ++dct)                                     \
            _Pragma("unroll")                                                 \
            for (int r = 0; r < 4; ++r) oacc[rt][dct][r] *= alpha[r];         \
    }                                                                         \
    __builtin_amdgcn_s_setprio(1);                                            \
    _Pragma("unroll")                                                         \
    for (int ks2 = 0; ks2 < 2; ++ks2) {                                       \
        half8 pa[2];                                                          \
        _Pragma("unroll")                                                     \
        for (int rt = 0; rt < 2; ++rt) {                                      \
            const int qq = rt * 16 + l15;                                     \
            const int chR = (ks2 * 4 + lg) ^ ((l15 >> 2) << 1);               \
            pa[rt] = *(half8*)&Pl[pbase + qq * KVBLK + chR * 8];              \
        }                                                                     \
        _Pragma("unroll")                                                     \
        for (int dct = 0; dct < 4; ++dct) {                                   \
            const int d = dct * 16 + l15;                                     \
            half8 vf = *(half8*)&VtC[d * KVBLK +                              \
                        (((ks2 * 4 + lg) ^ (d & 7) ^ (d >> 3)) * 8)];         \
            _Pragma("unroll")                                                 \
            for (int rt = 0; rt < 2; ++rt)                                    \
                oacc[rt][dct] = __builtin_amdgcn_mfma_f32_16x16x32_f16(       \
                    pa[rt], vf, oacc[rt][dct], 0, 0, 0);                      \
        }                                                                     \
    }                                                                         \
    __builtin_amdgcn_s_setprio(0);                                            \
    if (PF) { V_STORE(VtN, va_, vb_); }                                       \
    __syncthreads();                                                          \
} while (0)

__global__ __launch_bounds__(256, 2) void attn_mfma_kernel(
    const f16* __restrict__ qkvh, f16* __restrict__ attnh)
{
    __shared__ f16 Kh0[KVBLK * HD];       // 8 KB
    __shared__ f16 Kh1[KVBLK * HD];       // 8 KB
    __shared__ f16 Vt0[HD * KVBLK];       // 8 KB  [d][k]
    __shared__ f16 Vt1[HD * KVBLK];       // 8 KB
    __shared__ f16 Pl[4 * 32 * KVBLK];    // 16 KB per-wave [q][k]

    const int tid  = threadIdx.x;
    const int lane = tid & 63;
    const int wave = tid >> 6;
    const int l15  = lane & 15;
    const int lg   = lane >> 4;

    const int nq  = SEQ / QBLK;           // 16
    const int bid = blockIdx.x;
    const int b   = bid / (NH * nq);
    const int h   = (bid / nq) % NH;
    const int qc  = bid % nq;
    const int q0  = qc * QBLK + wave * 32;
    const size_t bS = (size_t)b * SEQ;

    // K staging geometry: instr covers 8 rows x 8 chunks; row&7 == krow_l
    const int krow_l = lane >> 3;         // 0..7
    const int kschk  = (lane & 7) ^ krow_l;
    const f16* kxsrc = qkvh + bS * D3 + DM + h * HD + kschk * 8;

    // V staging geometry: thread = 2 k-rows x 8 d
    const int vp  = tid >> 3;             // 0..31
    const int vd0 = (tid & 7) * 8;
    const f16* vsrc0 = qkvh + (bS + 2 * vp) * D3 + 2 * DM + h * HD + vd0;

    // Q fragments
    half8 qf[2][2];
#pragma unroll
    for (int rt = 0; rt < 2; ++rt)
#pragma unroll
        for (int ks = 0; ks < 2; ++ks)
            qf[rt][ks] = *(const half8*)&qkvh[(bS + q0 + rt * 16 + l15) * D3 +
                                              h * HD + ks * 32 + lg * 8];

    f32x4 oacc[2][4];
#pragma unroll
    for (int rt = 0; rt < 2; ++rt)
#pragma unroll
        for (int dct = 0; dct < 4; ++dct) oacc[rt][dct] = (f32x4){0.f, 0.f, 0.f, 0.f};

    float mrun[2][4], lrun[2][4];
#pragma unroll
    for (int rt = 0; rt < 2; ++rt)
#pragma unroll
        for (int r = 0; r < 4; ++r) { mrun[rt][r] = -INFINITY; lrun[rt][r] = 0.f; }

    const int pbase = wave * 32 * KVBLK;

    // prologue: stage tile 0 into buf0
    {
        async_cp16(kxsrc + (size_t)(wave * 16 +     krow_l) * D3, &Kh0[(wave * 16) * HD]);
        async_cp16(kxsrc + (size_t)(wave * 16 + 8 + krow_l) * D3, &Kh0[(wave * 16 + 8) * HD]);
        half8 va_ = *(const half8*)(vsrc0);
        half8 vb_ = *(const half8*)(vsrc0 + D3);
        V_STORE(Vt0, va_, vb_);
        __syncthreads();   // drains gload vmcnt + publishes Vt0
    }

    for (int t = 0; t < NTILES; t += 2) {
        ATTN_STEP(Kh0, Vt0, Kh1, Vt1, t, true);
        ATTN_STEP(Kh1, Vt1, Kh0, Vt0, t + 1, (t + 1) < (NTILES - 1));
    }

    // epilogue
#pragma unroll
    for (int rt = 0; rt < 2; ++rt) {
        float inv[4];
#pragma unroll
        for (int r = 0; r < 4; ++r) inv[r] = 1.f / lrun[rt][r];
#pragma unroll
        for (int dct = 0; dct < 4; ++dct)
#pragma unroll
            for (int r = 0; r < 4; ++r) {
                const int qq = q0 + rt * 16 + lg * 4 + r;
                attnh[(bS + qq) * DM + h * HD + dct * 16 + l15] =
                    (f16)(oacc[rt][dct][r] * inv[r]);
            }
    }
}

// ---------------------------------------------------------------------------
extern "C" void kernel_launch(void* const* d_in, const int* in_sizes, int n_in,
                              void* d_out, int out_size, void* d_ws, size_t ws_size,
                              hipStream_t stream) {
    const float* q    = (const float*)d_in[0];
    const float* k    = (const float*)d_in[1];
    const float* v    = (const float*)d_in[2];
    const float* Wqkv = (const float*)d_in[3];
    const float* bqkv = (const float*)d_in[4];
    const float* Wo   = (const float*)d_in[5];
    const float* bo   = (const float*)d_in[6];
    float* out = (float*)d_out;

    char* ws = (char*)d_ws;
    f16* Ain    = (f16*)ws;                        // [4096][3072]
    f16* attn_h = (f16*)ws;                        // [4096][1024] (reuse)
    f16* Wo_h   = (f16*)(ws + 16777216);           // [1024][1024] (reuse)
    f16* Wqkv_h = (f16*)(ws + 25165824);           // [3072][3072]
    f16* qkv_h  = (f16*)(ws + 44040192);           // [4096][3072]

    conv_concat_kernel<<<dim3(3, MROWS), 256, 0, stream>>>(q, k, v, Ain);
    conv_plain_kernel<<<2048, 256, 0, stream>>>(Wqkv, Wqkv_h, D3 * D3 / 4);

    gemm_f16_kernel<D3, D3, true><<<dim3((MROWS / 128) * (D3 / 128)), 256, 0, stream>>>(
        Ain, Wqkv_h, bqkv, qkv_h);

    attn_mfma_kernel<<<dim3(BS * NH * (SEQ / QBLK)), 256, 0, stream>>>(qkv_h, attn_h);

    conv_plain_kernel<<<512, 256, 0, stream>>>(Wo, Wo_h, DM * DM / 4);

    gemm_f16_kernel<DM, DM, false><<<dim3((MROWS / 128) * (DM / 128)), 256, 0, stream>>>(
        attn_h, Wo_h, bo, out);
}